// Round 4
// baseline (365.511 us; speedup 1.0000x reference)
//
#include <hip/hip_runtime.h>

// Swin window attention, two-kernel design (R4 = R3 + LDS stride bugfix):
//   prep:       weights -> bf16 transposed; bias -> 4 precomputed [64][64] f32 variants.
//   attn (K1):  per (window, head-pair) block, 256 thr / 4 waves.
//               R3 BUG: q_s/k_s declared [64][40] but written with 64 channels
//               -> address collisions corrupted ~1/3 of q/k (absmax 4.7e-3).
//               Fixed: stride 72 (144B rows: 16B-aligned b128 reads, 2-way-free
//               banks). LDS 46592 B -> 3 blocks/CU (12 independent waves/CU).
//               Softmax fused in-register; oa written bf16 to workspace.
//   proj (K2):  out-projection GEMM + bias + roll-back scatter. Memory-bound.
//
// MFMA 16x16x32 bf16 fragment layouts (HW-verified per guide m89/m91/m120):
//   A[m][k]: m = lane&15, k = (lane>>4)*8 + j   (8 contiguous bf16 = 16B)
//   B[k][n]: n = lane&15, k = (lane>>4)*8 + j
//   D[m][n]: n = lane&15, m = (lane>>4)*4 + reg

typedef __bf16 bf16x8 __attribute__((ext_vector_type(8)));
typedef short  s16x8  __attribute__((ext_vector_type(8)));
typedef float  f32x4  __attribute__((ext_vector_type(4)));

static __device__ __forceinline__ unsigned short f2bf(float f) {
  unsigned x = __builtin_bit_cast(unsigned, f);
  x += 0x7FFFu + ((x >> 16) & 1u);   // round-to-nearest-even
  return (unsigned short)(x >> 16);
}
static __device__ __forceinline__ f32x4 mfma16(s16x8 a, s16x8 b, f32x4 c) {
  return __builtin_amdgcn_mfma_f32_16x16x32_bf16(
      __builtin_bit_cast(bf16x8, a), __builtin_bit_cast(bf16x8, b), c, 0, 0, 0);
}

// ---------------- prep: weights (bf16, transposed) + bias variants ----------
__global__ void prep(const float* __restrict__ wqkv,
                     const float* __restrict__ wout,
                     const float* __restrict__ pe,
                     const float* __restrict__ ulm,
                     const float* __restrict__ lrm,
                     unsigned short* __restrict__ wqkvT,
                     unsigned short* __restrict__ woutT,
                     float* __restrict__ bias_g) {
  int idx = blockIdx.x * 256 + threadIdx.x;
  if (idx < 49152) {
    int n = idx >> 7, k = idx & 127;
    wqkvT[idx] = f2bf(wqkv[k * 384 + n]);
  } else if (idx < 65536) {
    int i2 = idx - 49152;
    int n = i2 >> 7, k = i2 & 127;
    woutT[i2] = f2bf(wout[k * 128 + n]);
  } else {
    int i3 = idx - 65536;                  // < 16384
    int var = i3 >> 12, t = i3 & 4095;
    int i = t >> 6, j = t & 63;
    int r0 = (j >> 3) - (i >> 3) + 7;
    int r1 = (j & 7) - (i & 7) + 7;
    float v = pe[r0 * 15 + r1];
    if (var & 2) v += ulm[t];
    if (var & 1) v += lrm[t];
    bias_g[i3] = v;
  }
}

// ---------------- K1: QKV + attention per (window, head-pair) ---------------
// LDS map (bytes):
//   xs [64][136] bf16 (17408) / P [2][64][72] bf16 (18432)   @ 0      (union)
//   q  [64][72]  bf16   9216                                 @ 18432
//   k  [64][72]  bf16   9216                                 @ 27648
//   v  [64ch][72] bf16  9216  (transposed [chloc][tok])      @ 36864
//   rsum [2][64] f32     512                                 @ 46080
//   total 46592  -> 3 blocks/CU.  oa [64][72] (9216) reuses q @ 18432.
#define K1_OFF_P   0
#define K1_OFF_Q   18432
#define K1_OFF_K   27648
#define K1_OFF_V   36864
#define K1_OFF_RS  46080
#define K1_SMEM    46592

__global__ __launch_bounds__(256, 3)
void swin_attn(const float* __restrict__ x,
               const unsigned short* __restrict__ wqkvT,
               const float* __restrict__ bias_g,
               unsigned short* __restrict__ oa_ws) {
  __shared__ __align__(16) unsigned char smem[K1_SMEM];
  unsigned short* xs_s = (unsigned short*)(smem + K1_OFF_P);  // phase 0-1
  unsigned short* P_s  = (unsigned short*)(smem + K1_OFF_P);  // phase 2+
  unsigned short* q_s  = (unsigned short*)(smem + K1_OFF_Q);
  unsigned short* k_s  = (unsigned short*)(smem + K1_OFF_K);
  unsigned short* oa_s = (unsigned short*)(smem + K1_OFF_Q);  // phase 4+
  unsigned short* v_s  = (unsigned short*)(smem + K1_OFF_V);
  float*          rsum_s = (float*)(smem + K1_OFF_RS);

  const int tid  = threadIdx.x;
  const int lane = tid & 63;
  const int wave = tid >> 6;       // 0..3
  const int ln15 = lane & 15;
  const int quad = lane >> 4;
  const int m_sub = quad << 2;

  const int bid = blockIdx.x;            // 16 * 256 * 2
  const int b   = bid >> 9;
  const int rem = bid & 511;
  const int win = rem >> 1;
  const int hp  = rem & 1;               // head pair: heads {2hp, 2hp+1}
  const int wh  = win >> 4, ww = win & 15;

  // ---- phase 0: stage rolled x window to LDS (bf16) ----
  {
    const int row0 = wh * 8, col0 = ww * 8;
#pragma unroll
    for (int it = 0; it < 8; ++it) {
      int t = tid + it * 256;              // 2048 float4 chunks
      int tok = t >> 5, c4 = t & 31;
      int ti = tok >> 3, tj = tok & 7;
      int gi = (row0 + ti + 4) & 127;
      int gj = (col0 + tj + 4) & 127;
      float4 v4 = *(const float4*)(x + (((b * 128 + gi) * 128 + gj) * 128 + c4 * 4));
      ushort4 pk;
      pk.x = f2bf(v4.x); pk.y = f2bf(v4.y); pk.z = f2bf(v4.z); pk.w = f2bf(v4.w);
      *(ushort4*)(xs_s + tok * 136 + c4 * 4) = pk;
    }
  }
  __syncthreads();

  // ---- phase 1: QKV GEMM for this head pair (M=64, K=128, N=192) ----------
  // 12 n-tiles over 4 waves: wave does nt = {wave, wave+4, wave+8} = q/k/v.
  {
#pragma unroll
    for (int i = 0; i < 3; ++i) {
      int nt  = wave + 4 * i;
      int sel = nt >> 2;                  // 0=q 1=k 2=v (wave-uniform)
      int ntl = nt & 3;
      int nloc  = ntl * 16 + ln15;        // 0..63 within head pair
      int nglob = sel * 128 + hp * 64 + nloc;
      s16x8 bfr[4];
      const unsigned short* wp = wqkvT + nglob * 128 + quad * 8;
#pragma unroll
      for (int ks = 0; ks < 4; ++ks) bfr[ks] = *(const s16x8*)(wp + ks * 32);
#pragma unroll
      for (int mt = 0; mt < 4; ++mt) {
        f32x4 acc = {0.f, 0.f, 0.f, 0.f};
#pragma unroll
        for (int ks = 0; ks < 4; ++ks) {
          s16x8 a = *(const s16x8*)(xs_s + (mt * 16 + ln15) * 136 + ks * 32 + quad * 8);
          acc = mfma16(a, bfr[ks], acc);
        }
        int tok0 = mt * 16 + m_sub;
        if (sel == 0) {
#pragma unroll
          for (int r = 0; r < 4; ++r) q_s[(tok0 + r) * 72 + nloc] = f2bf(acc[r]);
        } else if (sel == 1) {
#pragma unroll
          for (int r = 0; r < 4; ++r) k_s[(tok0 + r) * 72 + nloc] = f2bf(acc[r]);
        } else {
          ushort4 pk;
          pk.x = f2bf(acc[0]); pk.y = f2bf(acc[1]);
          pk.z = f2bf(acc[2]); pk.w = f2bf(acc[3]);
          *(ushort4*)(v_s + nloc * 72 + tok0) = pk;   // [chloc][tok]
        }
      }
    }
  }
  __syncthreads();

  // ---- phase 2+3 fused: S = QK^T*scale + bias, softmax in-register -> P ---
  // Wave -> (hloc = wave>>1, m-tiles {2*(wave&1), 2*(wave&1)+1}).
  {
    const int hloc = wave >> 1;
    const int mtb  = (wave & 1) * 2;
    const int var  = ((wh == 15) ? 2 : 0) | ((ww == 15) ? 1 : 0);
    const float* bg = bias_g + var * 4096;
    const float scale = 0.17677669529663687f;   // 32^-0.5
#pragma unroll
    for (int mi = 0; mi < 2; ++mi) {
      int mt = mtb + mi;
      s16x8 qf = *(const s16x8*)(q_s + (mt * 16 + ln15) * 72 + hloc * 32 + quad * 8);
      f32x4 acc[4];
#pragma unroll
      for (int nt = 0; nt < 4; ++nt) {
        s16x8 kf = *(const s16x8*)(k_s + (nt * 16 + ln15) * 72 + hloc * 32 + quad * 8);
        f32x4 z = {0.f, 0.f, 0.f, 0.f};
        acc[nt] = mfma16(qf, kf, z);
      }
      // rows: mt*16 + m_sub + r ; cols: nt*16 + ln15
      float sc[4][4];                     // [r][nt]
#pragma unroll
      for (int r = 0; r < 4; ++r) {
        int row = mt * 16 + m_sub + r;
#pragma unroll
        for (int nt = 0; nt < 4; ++nt)
          sc[r][nt] = acc[nt][r] * scale + bg[row * 64 + nt * 16 + ln15];
      }
      float sm[4];
#pragma unroll
      for (int r = 0; r < 4; ++r) {
        float m0 = fmaxf(fmaxf(sc[r][0], sc[r][1]), fmaxf(sc[r][2], sc[r][3]));
#pragma unroll
        for (int d = 1; d < 16; d <<= 1) m0 = fmaxf(m0, __shfl_xor(m0, d));
        float s0 = 0.f;
#pragma unroll
        for (int nt = 0; nt < 4; ++nt) {
          float e = __expf(sc[r][nt] - m0);
          sc[r][nt] = e;
          s0 += e;
        }
#pragma unroll
        for (int d = 1; d < 16; d <<= 1) s0 += __shfl_xor(s0, d);
        sm[r] = s0;
      }
      unsigned short* Ph = P_s + hloc * 64 * 72;
#pragma unroll
      for (int r = 0; r < 4; ++r) {
        int row = mt * 16 + m_sub + r;
#pragma unroll
        for (int nt = 0; nt < 4; ++nt)
          Ph[row * 72 + nt * 16 + ln15] = f2bf(sc[r][nt]);
        if (ln15 == 0) rsum_s[hloc * 64 + row] = 1.0f / sm[r];
      }
    }
  }
  __syncthreads();

  // ---- phase 4: PV (per head: M=64 tok, K=64 keys, N=32 ch) -> oa LDS -----
  // Wave -> (hloc = wave>>1, ntv = wave&1), loops mt 0..3.
  {
    const int hloc = wave >> 1;
    const int ntv  = wave & 1;
    const unsigned short* Ph = P_s + hloc * 64 * 72;
    s16x8 vf[2];
#pragma unroll
    for (int ks = 0; ks < 2; ++ks)
      vf[ks] = *(const s16x8*)(v_s + (hloc * 32 + ntv * 16 + ln15) * 72 + ks * 32 + quad * 8);
#pragma unroll
    for (int mt = 0; mt < 4; ++mt) {
      f32x4 acc = {0.f, 0.f, 0.f, 0.f};
#pragma unroll
      for (int ks = 0; ks < 2; ++ks) {
        s16x8 pf = *(const s16x8*)(Ph + (mt * 16 + ln15) * 72 + ks * 32 + quad * 8);
        acc = mfma16(pf, vf[ks], acc);
      }
      int tok0 = mt * 16 + m_sub;
      int cloc = hloc * 32 + ntv * 16 + ln15;     // 0..63
#pragma unroll
      for (int r = 0; r < 4; ++r)
        oa_s[(tok0 + r) * 72 + cloc] = f2bf(acc[r] * rsum_s[hloc * 64 + tok0 + r]);
    }
  }
  __syncthreads();

  // ---- phase 5: oa LDS -> global ws, contiguous per (win, hp) -------------
  {
    unsigned short* dst = oa_ws + (((size_t)b * 512 + win * 2 + hp) * 64) * 64;
#pragma unroll
    for (int it = 0; it < 2; ++it) {
      int idx = tid + it * 256;            // 512 x 16B chunks
      int row = idx >> 3, c = idx & 7;
      *(s16x8*)(dst + row * 64 + c * 8) = *(const s16x8*)(oa_s + row * 72 + c * 8);
    }
  }
}

// ---------------- K2: out projection + bias + roll-back ---------------------
__global__ __launch_bounds__(256, 4)
void swin_proj(const unsigned short* __restrict__ oa_ws,
               const unsigned short* __restrict__ woutT,
               const float* __restrict__ b_out,
               float* __restrict__ out) {
  __shared__ __align__(16) unsigned short oa_s[64 * 136];

  const int tid  = threadIdx.x;
  const int lane = tid & 63;
  const int wave = tid >> 6;
  const int ln15 = lane & 15;
  const int quad = lane >> 4;
  const int m_sub = quad << 2;

  const int bid = blockIdx.x;            // 16*256
  const int b   = bid >> 8;
  const int win = bid & 255;
  const int wh  = win >> 4, ww = win & 15;

  // stage oa window (both head pairs) into [tok][ch global] layout
  {
    const unsigned short* src = oa_ws + (((size_t)b * 512 + win * 2) * 64) * 64;
#pragma unroll
    for (int it = 0; it < 4; ++it) {
      int idx = tid + it * 256;            // 1024 x 16B chunks
      int hp  = idx >> 9;
      int tok = (idx >> 3) & 63;
      int c   = idx & 7;
      *(s16x8*)(oa_s + tok * 136 + hp * 64 + c * 8) =
          *(const s16x8*)(src + ((size_t)hp * 64 + tok) * 64 + c * 8);
    }
  }
  __syncthreads();

#pragma unroll
  for (int ni = 0; ni < 2; ++ni) {
    int n = (wave * 2 + ni) * 16 + ln15;
    s16x8 bfr[4];
    const unsigned short* wp = woutT + n * 128 + quad * 8;
#pragma unroll
    for (int ks = 0; ks < 4; ++ks) bfr[ks] = *(const s16x8*)(wp + ks * 32);
    float bo = b_out[n];
#pragma unroll
    for (int mt = 0; mt < 4; ++mt) {
      f32x4 acc = {0.f, 0.f, 0.f, 0.f};
#pragma unroll
      for (int ks = 0; ks < 4; ++ks) {
        s16x8 a = *(const s16x8*)(oa_s + (mt * 16 + ln15) * 136 + ks * 32 + quad * 8);
        acc = mfma16(a, bfr[ks], acc);
      }
      int tok0 = mt * 16 + m_sub;
#pragma unroll
      for (int r = 0; r < 4; ++r) {
        int tok = tok0 + r;
        int ti = tok >> 3, tj = tok & 7;
        int gi = (wh * 8 + ti + 4) & 127;
        int gj = (ww * 8 + tj + 4) & 127;
        out[((b * 128 + gi) * 128 + gj) * 128 + n] = acc[r] + bo;
      }
    }
  }
}

extern "C" void kernel_launch(void* const* d_in, const int* in_sizes, int n_in,
                              void* d_out, int out_size, void* d_ws, size_t ws_size,
                              hipStream_t stream) {
  const float* x    = (const float*)d_in[0];
  const float* wqkv = (const float*)d_in[1];
  const float* wout = (const float*)d_in[2];
  const float* bout = (const float*)d_in[3];
  const float* pe   = (const float*)d_in[4];
  const float* ulm  = (const float*)d_in[5];
  const float* lrm  = (const float*)d_in[6];

  // workspace layout
  unsigned short* wqkvT = (unsigned short*)d_ws;            // 384*128
  unsigned short* woutT = wqkvT + 49152;                    // 128*128
  float*          bias_g = (float*)(woutT + 16384);         // 4*64*64 f32
  unsigned short* oa_ws  = (unsigned short*)(bias_g + 16384); // 16*512*64*64 bf16 (64MB)

  prep<<<320, 256, 0, stream>>>(wqkv, wout, pe, ulm, lrm, wqkvT, woutT, bias_g);
  swin_attn<<<16 * 256 * 2, 256, 0, stream>>>(x, wqkvT, bias_g, oa_ws);
  swin_proj<<<16 * 256, 256, 0, stream>>>(oa_ws, woutT, bout, (float*)d_out);
}